// Round 11
// baseline (142.369 us; speedup 1.0000x reference)
//
#include <hip/hip_runtime.h>
#include <hip/hip_bf16.h>

#define BB 2
#define NN 32768
#define CC 256
#define SN 16
#define MM 2048          // NN/SN
#define HH 8
#define HD 32
#define PP1 4            // nn-partitions for denominator pass
#define PPB 4            // mm-partitions for output pass
#define QSCALE 0.17677669529663687f   // 1/sqrt(32)
#define AFFSCALE 0.0625f              // C^-0.5

typedef unsigned short u16;
typedef __attribute__((ext_vector_type(8))) short bf16x8;
typedef __attribute__((ext_vector_type(4))) float f32x4;
typedef __attribute__((ext_vector_type(4))) unsigned short u16x4;

// RNE float->bf16 bits
__device__ __forceinline__ u16 f2bfu(float x) {
    unsigned u = __float_as_uint(x);
    u = (u + 0x7fff + ((u >> 16) & 1)) >> 16;
    return (u16)u;
}

// K1: sf[b,j,c] = mean over 16 tokens
__global__ void k1_sf(const float* __restrict__ x, float* __restrict__ sf) {
    int blk = blockIdx.x;           // b*MM + j
    int b = blk / MM, j = blk % MM;
    int c = threadIdx.x;
    const float* xp = x + ((size_t)(b*NN + j*SN))*CC + c;
    float s = 0.f;
    #pragma unroll
    for (int i = 0; i < SN; ++i) s += xp[i*CC];
    sf[(size_t)blk*CC + c] = s * (1.0f/16.0f);
}

// K2P: aff[b,j,i,k] = softmax_k( pix . sf[j+k-1] * scale )
//  + fold partials local to this block:
//    P[b,j,k,c] = sum_i x[j,i,c]*aff[j,i,k]
//    A[b,j,k]   = sum_i aff[j,i,k]
__global__ void k2p_aff(const float* __restrict__ x, const float* __restrict__ sf,
                        float* __restrict__ aff, float* __restrict__ P,
                        float* __restrict__ A) {
    int blk = blockIdx.x; int b = blk / MM, j = blk % MM;
    __shared__ float sfl[3][CC];
    __shared__ float xl[SN][CC];
    __shared__ float affl[SN][3];
    int tid = threadIdx.x;
    #pragma unroll
    for (int k = 0; k < 3; ++k) {
        int w = j + k - 1;
        sfl[k][tid] = (w >= 0 && w < MM) ? sf[((size_t)b*MM + w)*CC + tid] : 0.f;
    }
    for (int idx = tid; idx < SN*64; idx += 256) {
        int i = idx >> 6, c4 = (idx & 63) << 2;
        *(float4*)&xl[i][c4] = *(const float4*)&x[((size_t)(b*NN + j*SN + i))*CC + c4];
    }
    __syncthreads();
    int wave = tid >> 6, lane = tid & 63;
    for (int qi = 0; qi < 4; ++qi) {
        int i = wave*4 + qi;
        float d0=0.f, d1=0.f, d2=0.f;
        #pragma unroll
        for (int cq = 0; cq < 4; ++cq) {
            int c = lane + cq*64;
            float xv = xl[i][c];
            d0 += xv * sfl[0][c];
            d1 += xv * sfl[1][c];
            d2 += xv * sfl[2][c];
        }
        #pragma unroll
        for (int off = 32; off >= 1; off >>= 1) {
            d0 += __shfl_xor(d0, off, 64);
            d1 += __shfl_xor(d1, off, 64);
            d2 += __shfl_xor(d2, off, 64);
        }
        if (lane == 0) {
            float l0 = d0*AFFSCALE, l1 = d1*AFFSCALE, l2 = d2*AFFSCALE;
            float mx = fmaxf(l0, fmaxf(l1, l2));
            float e0 = __expf(l0-mx), e1 = __expf(l1-mx), e2 = __expf(l2-mx);
            float inv = 1.0f/(e0+e1+e2);
            float a0 = e0*inv, a1 = e1*inv, a2 = e2*inv;
            size_t base = ((size_t)blk*SN + i)*3;
            aff[base+0] = a0; aff[base+1] = a1; aff[base+2] = a2;
            affl[i][0] = a0; affl[i][1] = a1; affl[i][2] = a2;
        }
    }
    __syncthreads();
    {
        int c = tid;
        #pragma unroll
        for (int k = 0; k < 3; ++k) {
            float p = 0.f;
            #pragma unroll
            for (int i = 0; i < SN; ++i) p += xl[i][c] * affl[i][k];
            P[((size_t)blk*3 + k)*CC + c] = p;
        }
        if (tid < 3) {
            float a = 0.f;
            #pragma unroll
            for (int i = 0; i < SN; ++i) a += affl[i][tid];
            A[(size_t)blk*3 + tid] = a;
        }
    }
}

// K4a (MFMA, fused fold/normalize): sf2 assembled inline from P/A partials.
__global__ void k4a_mfma(const float* __restrict__ P, const float* __restrict__ A,
                         const float* __restrict__ wqkv,
                         u16* __restrict__ qh, u16* __restrict__ kh, u16* __restrict__ vth) {
    int mt = blockIdx.x, ot = blockIdx.y, b = blockIdx.z;
    int mm0 = mt*64, oo0 = ot*64;
    __shared__ u16 S[64][264];
    __shared__ u16 W[64][264];
    __shared__ float dn[64];
    int tid = threadIdx.x;
    if (tid < 64) {
        int m = mm0 + tid;
        float a0 = (m+1 < MM) ? A[((size_t)(b*MM + m+1))*3 + 0] : 0.f;
        float a1 =               A[((size_t)(b*MM + m  ))*3 + 1];
        float a2 = (m-1 >= 0)  ? A[((size_t)(b*MM + m-1))*3 + 2] : 0.f;
        dn[tid] = ((a0 + a1) + a2) + 1e-12f;
    }
    __syncthreads();
    const float* Pb = P + (size_t)b*MM*3*CC;
    for (int idx = tid; idx < 64*64; idx += 256) {
        int r = idx >> 6, c4 = (idx & 63) << 2;
        int m = mm0 + r;
        float4 p0 = make_float4(0.f,0.f,0.f,0.f), p2 = make_float4(0.f,0.f,0.f,0.f);
        if (m+1 < MM) p0 = *(const float4*)&Pb[((size_t)(m+1)*3 + 0)*CC + c4];
        float4 p1 = *(const float4*)&Pb[((size_t)m*3 + 1)*CC + c4];
        if (m-1 >= 0) p2 = *(const float4*)&Pb[((size_t)(m-1)*3 + 2)*CC + c4];
        float d = dn[r];
        float sx = ((p0.x+p1.x)+p2.x)/d, sy = ((p0.y+p1.y)+p2.y)/d;
        float sz = ((p0.z+p1.z)+p2.z)/d, sw = ((p0.w+p1.w)+p2.w)/d;
        *(u16x4*)&S[r][c4] = (u16x4){f2bfu(sx), f2bfu(sy), f2bfu(sz), f2bfu(sw)};
        float4 wv = *(const float4*)&wqkv[(size_t)(oo0 + r)*CC + c4];
        *(u16x4*)&W[r][c4] = (u16x4){f2bfu(wv.x), f2bfu(wv.y), f2bfu(wv.z), f2bfu(wv.w)};
    }
    __syncthreads();
    int w = tid >> 6, l = tid & 63;
    f32x4 acc[4] = {{0.f,0.f,0.f,0.f},{0.f,0.f,0.f,0.f},{0.f,0.f,0.f,0.f},{0.f,0.f,0.f,0.f}};
    #pragma unroll
    for (int kc = 0; kc < 8; ++kc) {
        bf16x8 bf = *(const bf16x8*)&W[w*16 + (l&15)][kc*32 + ((l>>4)<<3)];
        #pragma unroll
        for (int nt = 0; nt < 4; ++nt) {
            bf16x8 af = *(const bf16x8*)&S[nt*16 + (l&15)][kc*32 + ((l>>4)<<3)];
            acc[nt] = __builtin_amdgcn_mfma_f32_16x16x32_bf16(af, bf, acc[nt], 0, 0, 0);
        }
    }
    int o = oo0 + w*16 + (l&15);
    int h = o / 96, rr = o % 96;
    int bh = b*HH + h;
    int m0 = mm0 + ((l>>4)<<2);
    #pragma unroll
    for (int nt = 0; nt < 4; ++nt) {
        #pragma unroll
        for (int r = 0; r < 4; ++r) {
            int m = m0 + nt*16 + r;
            float v = acc[nt][r];
            if (rr < 32)      qh[((size_t)bh*MM + m)*HD + rr]       = f2bfu(v * QSCALE);
            else if (rr < 64) kh[((size_t)bh*MM + m)*HD + (rr-32)]  = f2bfu(v);
            else              vth[((size_t)bh*HD + (rr-64))*MM + m] = f2bfu(v);
        }
    }
}

// K4b (MFMA, nn-partitioned): ses[p][bh][mm] = sum over nn-partition of exp(k_mm . q_nn)
// Whole 512-row Q-partition staged ONCE (40 KB LDS, 1 barrier); zero in-loop barriers.
__global__ void k4b_mfma(const u16* __restrict__ qh, const u16* __restrict__ kh,
                         float* __restrict__ ses) {
    int bx = blockIdx.x;
    int p = blockIdx.y;
    int bh = bx >> 5;                 // MM/64 = 32 tiles
    int mt = bx & 31;
    int mm0 = mt * 64;
    int tid = threadIdx.x, w = tid >> 6, l = tid & 63;
    bf16x8 af = *(const bf16x8*)&kh[((size_t)bh*MM + mm0 + w*16 + (l&15))*HD + ((l>>4)<<3)];
    __shared__ u16 Qlds[512][40];     // 40 KB
    int nnbeg = p * (MM/PP1);
    for (int idx = tid; idx < 512*4; idx += 256) {
        int r = idx >> 2, ch = idx & 3;
        *(bf16x8*)&Qlds[r][ch*8] =
            *(const bf16x8*)&qh[((size_t)bh*MM + nnbeg + r)*HD + ch*8];
    }
    __syncthreads();
    float rs0=0.f, rs1=0.f, rs2=0.f, rs3=0.f;
    for (int t = 0; t < 8; ++t) {
        #pragma unroll
        for (int nt = 0; nt < 4; ++nt) {
            bf16x8 bf = *(const bf16x8*)&Qlds[t*64 + nt*16 + (l&15)][(l>>4)<<3];
            f32x4 acc = {0.f,0.f,0.f,0.f};
            acc = __builtin_amdgcn_mfma_f32_16x16x32_bf16(af, bf, acc, 0, 0, 0);
            rs0 += __expf(acc[0]); rs1 += __expf(acc[1]);
            rs2 += __expf(acc[2]); rs3 += __expf(acc[3]);
        }
    }
    float rs[4] = {rs0, rs1, rs2, rs3};
    #pragma unroll
    for (int r = 0; r < 4; ++r) {
        float v = rs[r];
        v += __shfl_xor(v, 1, 64);
        v += __shfl_xor(v, 2, 64);
        v += __shfl_xor(v, 4, 64);
        v += __shfl_xor(v, 8, 64);
        if ((l & 15) == 0)
            ses[((size_t)p*BB*HH + bh)*MM + mm0 + w*16 + ((l>>4)<<2) + r] = v;
    }
}

// K4c (MFMA, mm-partitioned, 128-nn blocks, direct Q/K frag loads):
//   part[p][b][nn][h*32+d] = sum over mm-partition of exp(k_mm.q_nn)*(1/sum_p ses)*v[mm][d]
__global__ void k4c_mfma(const u16* __restrict__ qh, const u16* __restrict__ kh,
                         const u16* __restrict__ vth, const float* __restrict__ ses,
                         float* __restrict__ part) {
    int bx = blockIdx.x;
    int p = blockIdx.y;
    int bh = bx >> 4;                 // MM/128 = 16 ntiles
    int ntile = bx & 15;
    int nn0 = ntile * 128;
    int b = bh >> 3, h = bh & 7;
    int tid = threadIdx.x, w = tid >> 6, l = tid & 63;
    bf16x8 qf[8];
    #pragma unroll
    for (int nt = 0; nt < 8; ++nt)
        qf[nt] = *(const bf16x8*)&qh[((size_t)bh*MM + nn0 + nt*16 + (l&15))*HD + ((l>>4)<<3)];
    __shared__ u16 Vtlds[32][72];
    __shared__ u16 Wlds[128][72];
    __shared__ float Rlds[64];
    f32x4 oa0 = {0.f,0.f,0.f,0.f}, oa1 = {0.f,0.f,0.f,0.f};
    f32x4 ob0 = {0.f,0.f,0.f,0.f}, ob1 = {0.f,0.f,0.f,0.f};
    int mmbeg = p * (MM/PPB), mmend = mmbeg + (MM/PPB);
    const size_t SESP = (size_t)BB*HH*MM;
    for (int mm0 = mmbeg; mm0 < mmend; mm0 += 64) {
        __syncthreads();
        {   // stage Vt-tile (32x64) + merged reciprocal denominators
            int d = tid >> 3, ch2 = tid & 7;
            *(bf16x8*)&Vtlds[d][ch2*8] =
                *(const bf16x8*)&vth[((size_t)bh*HD + d)*MM + mm0 + ch2*8];
            if (tid < 64) {
                size_t e = (size_t)bh*MM + mm0 + tid;
                float s = ses[e] + ses[SESP + e] + ses[2*SESP + e] + ses[3*SESP + e];
                Rlds[tid] = 1.0f / s;
            }
        }
        __syncthreads();
        {   // GEMM1: K-frag direct from L2; W = exp(S)*rinv -> Wlds[128 nn][64 mm]
            bf16x8 af = *(const bf16x8*)&kh[((size_t)bh*MM + mm0 + w*16 + (l&15))*HD + ((l>>4)<<3)];
            float ri[4];
            #pragma unroll
            for (int r = 0; r < 4; ++r) ri[r] = Rlds[w*16 + ((l>>4)<<2) + r];
            #pragma unroll
            for (int nt = 0; nt < 8; ++nt) {
                f32x4 s = {0.f,0.f,0.f,0.f};
                s = __builtin_amdgcn_mfma_f32_16x16x32_bf16(af, qf[nt], s, 0, 0, 0);
                unsigned p0 = (unsigned)f2bfu(__expf(s[0]) * ri[0])
                            | ((unsigned)f2bfu(__expf(s[1]) * ri[1]) << 16);
                unsigned p1 = (unsigned)f2bfu(__expf(s[2]) * ri[2])
                            | ((unsigned)f2bfu(__expf(s[3]) * ri[3]) << 16);
                uint2 pk; pk.x = p0; pk.y = p1;
                *(uint2*)&Wlds[nt*16 + (l&15)][w*16 + ((l>>4)<<2)] = pk;
            }
        }
        __syncthreads();
        // GEMM2: both nn-halves
        #pragma unroll
        for (int ks = 0; ks < 2; ++ks) {
            bf16x8 b20 = *(const bf16x8*)&Vtlds[(l&15)][ks*32 + ((l>>4)<<3)];
            bf16x8 b21 = *(const bf16x8*)&Vtlds[16 + (l&15)][ks*32 + ((l>>4)<<3)];
            bf16x8 a2a = *(const bf16x8*)&Wlds[w*16 + (l&15)][ks*32 + ((l>>4)<<3)];
            bf16x8 a2b = *(const bf16x8*)&Wlds[64 + w*16 + (l&15)][ks*32 + ((l>>4)<<3)];
            oa0 = __builtin_amdgcn_mfma_f32_16x16x32_bf16(a2a, b20, oa0, 0, 0, 0);
            oa1 = __builtin_amdgcn_mfma_f32_16x16x32_bf16(a2a, b21, oa1, 0, 0, 0);
            ob0 = __builtin_amdgcn_mfma_f32_16x16x32_bf16(a2b, b20, ob0, 0, 0, 0);
            ob1 = __builtin_amdgcn_mfma_f32_16x16x32_bf16(a2b, b21, ob1, 0, 0, 0);
        }
    }
    int nna = nn0 + w*16 + ((l>>4)<<2);
    int dcol = h*32 + (l&15);
    float* op = part + ((size_t)p*BB + b)*((size_t)MM*CC);
    #pragma unroll
    for (int r = 0; r < 4; ++r) {
        op[((size_t)nna + r)*CC + dcol]           = oa0[r];
        op[((size_t)nna + r)*CC + dcol + 16]      = oa1[r];
        op[((size_t)nna + 64 + r)*CC + dcol]      = ob0[r];
        op[((size_t)nna + 64 + r)*CC + dcol + 16] = ob1[r];
    }
}

// K5 (MFMA, fused partial reduce): sf2r[b,o,m] = Wproj @ (sum_p part[p]) + bproj
__global__ void k5_mfma(const float* __restrict__ part, const float* __restrict__ wproj,
                        const float* __restrict__ bproj, float* __restrict__ sf2r) {
    int mt = blockIdx.x, ot = blockIdx.y, b = blockIdx.z;
    int mm0 = mt*64, oo0 = ot*64;
    __shared__ u16 S[64][264];
    __shared__ u16 W[64][264];
    int tid = threadIdx.x;
    const size_t PARTP = (size_t)BB*MM*CC;
    const float* pb = part + (size_t)b*MM*CC;
    for (int idx = tid; idx < 64*64; idx += 256) {
        int r = idx >> 6, c4 = (idx & 63) << 2;
        size_t e = (size_t)(mm0 + r)*CC + c4;
        float4 s0 = *(const float4*)&pb[e];
        float4 s1 = *(const float4*)&pb[PARTP + e];
        float4 s2 = *(const float4*)&pb[2*PARTP + e];
        float4 s3 = *(const float4*)&pb[3*PARTP + e];
        float sx = s0.x+s1.x+s2.x+s3.x, sy = s0.y+s1.y+s2.y+s3.y;
        float sz = s0.z+s1.z+s2.z+s3.z, sw = s0.w+s1.w+s2.w+s3.w;
        *(u16x4*)&S[r][c4] = (u16x4){f2bfu(sx), f2bfu(sy), f2bfu(sz), f2bfu(sw)};
        float4 wv = *(const float4*)&wproj[(size_t)(oo0 + r)*CC + c4];
        *(u16x4*)&W[r][c4] = (u16x4){f2bfu(wv.x), f2bfu(wv.y), f2bfu(wv.z), f2bfu(wv.w)};
    }
    __syncthreads();
    int w = tid >> 6, l = tid & 63;
    f32x4 acc[4] = {{0.f,0.f,0.f,0.f},{0.f,0.f,0.f,0.f},{0.f,0.f,0.f,0.f},{0.f,0.f,0.f,0.f}};
    #pragma unroll
    for (int kc = 0; kc < 8; ++kc) {
        bf16x8 bf = *(const bf16x8*)&W[w*16 + (l&15)][kc*32 + ((l>>4)<<3)];
        #pragma unroll
        for (int nt = 0; nt < 4; ++nt) {
            bf16x8 af = *(const bf16x8*)&S[nt*16 + (l&15)][kc*32 + ((l>>4)<<3)];
            acc[nt] = __builtin_amdgcn_mfma_f32_16x16x32_bf16(af, bf, acc[nt], 0, 0, 0);
        }
    }
    int o = oo0 + w*16 + (l&15);
    float bp = bproj[o];
    int m0 = mm0 + ((l>>4)<<2);
    #pragma unroll
    for (int nt = 0; nt < 4; ++nt) {
        #pragma unroll
        for (int r = 0; r < 4; ++r) {
            sf2r[((size_t)b*CC + o)*MM + m0 + nt*16 + r] = acc[nt][r] + bp;
        }
    }
}

// K6: out[b,c,j*16+i] = sum_k sf2r[b,c,j+k-1]*aff[b,j,i,k]  (fp32 output)
__global__ void k6_final(const float* __restrict__ sf2r, const float* __restrict__ aff,
                         float* __restrict__ out) {
    int jt = blockIdx.x, cq = blockIdx.y, b = blockIdx.z;
    int jb = jt*16, cq0 = cq*64;
    int tid = threadIdx.x;               // 256 tokens
    int jl = tid >> 4, il = tid & 15;
    int j = jb + jl;
    size_t abase = (((size_t)b*MM + j)*SN + il)*3;
    float a0 = aff[abase], a1 = aff[abase+1], a2 = aff[abase+2];
    __shared__ float stile[64][18];
    for (int idx = tid; idx < 64*18; idx += 256) {
        int cl = idx / 18, jo = idx % 18;
        int jj = jb - 1 + jo;
        stile[cl][jo] = (jj >= 0 && jj < MM) ? sf2r[((size_t)b*CC + cq0 + cl)*MM + jj] : 0.f;
    }
    __syncthreads();
    int t = jb*SN + tid;
    float* ob = out + (size_t)b*CC*NN + (size_t)cq0*NN + t;
    #pragma unroll 4
    for (int cl = 0; cl < 64; ++cl) {
        float v = stile[cl][jl]*a0 + stile[cl][jl+1]*a1 + stile[cl][jl+2]*a2;
        ob[(size_t)cl*NN] = v;
    }
}

extern "C" void kernel_launch(void* const* d_in, const int* in_sizes, int n_in,
                              void* d_out, int out_size, void* d_ws, size_t ws_size,
                              hipStream_t stream) {
    const float *x = nullptr, *wqkv = nullptr, *wproj = nullptr, *bproj = nullptr;
    for (int i = 0; i < n_in; ++i) {
        int sz = in_sizes[i];
        if (sz == BB*NN*CC)        x     = (const float*)d_in[i];
        else if (sz == 3*CC*CC)    wqkv  = (const float*)d_in[i];
        else if (sz == CC*CC)      wproj = (const float*)d_in[i];
        else if (sz == CC)         bproj = (const float*)d_in[i];
    }
    float* out = (float*)d_out;    // reference output dtype is float32
    char* ws = (char*)d_ws;
    const size_t MB = 1024*1024;
    // Workspace (28 MiB total; P aliases part — disjoint lifetimes)
    float* aff     = (float*)(ws);            // 0.75 MiB (k2p -> k6)
    float* sfbuf   = (float*)(ws + 1*MB);     // 4 MiB: sf (k1->k2p), then sf2r (k5->k6)
    u16*   qh      = (u16*)  (ws + 5*MB);     // 2 MiB bf16 [bh][m][32]
    u16*   kh      = (u16*)  (ws + 7*MB);     // 2 MiB bf16 [bh][m][32]
    u16*   vth     = (u16*)  (ws + 9*MB);     // 2 MiB bf16 [bh][32][m]
    float* ses     = (float*)(ws + 11*MB);    // 0.5 MiB (PP1 partials, k4b->k4c)
    float* A       = (float*)(ws + 11*MB + 512*1024);  // 48 KiB (k2p->k4a)
    float* P       = (float*)(ws + 12*MB);    // 12.6 MiB (k2p->k4a)
    float* part    = (float*)(ws + 12*MB);    // 16 MiB (k4c->k5), aliases P
    float* sf      = sfbuf;
    float* sf2r    = sfbuf;

    k1_sf   <<<BB*MM, 256, 0, stream>>>(x, sf);
    k2p_aff <<<BB*MM, 256, 0, stream>>>(x, sf, aff, P, A);
    k4a_mfma<<<dim3(MM/64, 12, BB), 256, 0, stream>>>(P, A, wqkv, qh, kh, vth);
    k4b_mfma<<<dim3(BB*HH*(MM/64), PP1), 256, 0, stream>>>(qh, kh, ses);
    k4c_mfma<<<dim3(BB*HH*(MM/128), PPB), 256, 0, stream>>>(qh, kh, vth, ses, part);
    k5_mfma <<<dim3(MM/64, 4, BB), 256, 0, stream>>>(part, wproj, bproj, sf2r);
    k6_final<<<dim3(MM/16, 4, BB), 256, 0, stream>>>(sf2r, aff, out);
}

// Round 12
// 127.219 us; speedup vs baseline: 1.1191x; 1.1191x over previous
//
#include <hip/hip_runtime.h>
#include <hip/hip_bf16.h>

#define BB 2
#define NN 32768
#define CC 256
#define SN 16
#define MM 2048          // NN/SN
#define HH 8
#define HD 32
#define PP1 4            // nn-partitions for denominator pass
#define PPB 4            // mm-partitions for output pass
#define QSCALE 0.17677669529663687f   // 1/sqrt(32)
#define AFFSCALE 0.0625f              // C^-0.5

typedef unsigned short u16;
typedef __attribute__((ext_vector_type(8))) short bf16x8;
typedef __attribute__((ext_vector_type(4))) float f32x4;
typedef __attribute__((ext_vector_type(4))) unsigned short u16x4;

// RNE float->bf16 bits
__device__ __forceinline__ u16 f2bfu(float x) {
    unsigned u = __float_as_uint(x);
    u = (u + 0x7fff + ((u >> 16) & 1)) >> 16;
    return (u16)u;
}

// K1: sf[b,j,c] = mean over 16 tokens
__global__ void k1_sf(const float* __restrict__ x, float* __restrict__ sf) {
    int blk = blockIdx.x;           // b*MM + j
    int b = blk / MM, j = blk % MM;
    int c = threadIdx.x;
    const float* xp = x + ((size_t)(b*NN + j*SN))*CC + c;
    float s = 0.f;
    #pragma unroll
    for (int i = 0; i < SN; ++i) s += xp[i*CC];
    sf[(size_t)blk*CC + c] = s * (1.0f/16.0f);
}

// K2P: aff[b,j,i,k] = softmax_k( pix . sf[j+k-1] * scale )
//  + fold partials local to this block:
//    P[b,j,k,c] = sum_i x[j,i,c]*aff[j,i,k]
//    A[b,j,k]   = sum_i aff[j,i,k]
__global__ void k2p_aff(const float* __restrict__ x, const float* __restrict__ sf,
                        float* __restrict__ aff, float* __restrict__ P,
                        float* __restrict__ A) {
    int blk = blockIdx.x; int b = blk / MM, j = blk % MM;
    __shared__ float sfl[3][CC];
    __shared__ float xl[SN][CC];
    __shared__ float affl[SN][3];
    int tid = threadIdx.x;
    #pragma unroll
    for (int k = 0; k < 3; ++k) {
        int w = j + k - 1;
        sfl[k][tid] = (w >= 0 && w < MM) ? sf[((size_t)b*MM + w)*CC + tid] : 0.f;
    }
    for (int idx = tid; idx < SN*64; idx += 256) {
        int i = idx >> 6, c4 = (idx & 63) << 2;
        *(float4*)&xl[i][c4] = *(const float4*)&x[((size_t)(b*NN + j*SN + i))*CC + c4];
    }
    __syncthreads();
    int wave = tid >> 6, lane = tid & 63;
    for (int qi = 0; qi < 4; ++qi) {
        int i = wave*4 + qi;
        float d0=0.f, d1=0.f, d2=0.f;
        #pragma unroll
        for (int cq = 0; cq < 4; ++cq) {
            int c = lane + cq*64;
            float xv = xl[i][c];
            d0 += xv * sfl[0][c];
            d1 += xv * sfl[1][c];
            d2 += xv * sfl[2][c];
        }
        #pragma unroll
        for (int off = 32; off >= 1; off >>= 1) {
            d0 += __shfl_xor(d0, off, 64);
            d1 += __shfl_xor(d1, off, 64);
            d2 += __shfl_xor(d2, off, 64);
        }
        if (lane == 0) {
            float l0 = d0*AFFSCALE, l1 = d1*AFFSCALE, l2 = d2*AFFSCALE;
            float mx = fmaxf(l0, fmaxf(l1, l2));
            float e0 = __expf(l0-mx), e1 = __expf(l1-mx), e2 = __expf(l2-mx);
            float inv = 1.0f/(e0+e1+e2);
            float a0 = e0*inv, a1 = e1*inv, a2 = e2*inv;
            size_t base = ((size_t)blk*SN + i)*3;
            aff[base+0] = a0; aff[base+1] = a1; aff[base+2] = a2;
            affl[i][0] = a0; affl[i][1] = a1; affl[i][2] = a2;
        }
    }
    __syncthreads();
    {
        int c = tid;
        #pragma unroll
        for (int k = 0; k < 3; ++k) {
            float p = 0.f;
            #pragma unroll
            for (int i = 0; i < SN; ++i) p += xl[i][c] * affl[i][k];
            P[((size_t)blk*3 + k)*CC + c] = p;
        }
        if (tid < 3) {
            float a = 0.f;
            #pragma unroll
            for (int i = 0; i < SN; ++i) a += affl[i][tid];
            A[(size_t)blk*3 + tid] = a;
        }
    }
}

// K4a (MFMA, fused fold/normalize): sf2 assembled inline from P/A partials.
//   sf2[m,c] = (P[m+1][0][c] + P[m][1][c] + P[m-1][2][c]) / (A-fold + 1e-12)
__global__ void k4a_mfma(const float* __restrict__ P, const float* __restrict__ A,
                         const float* __restrict__ wqkv,
                         u16* __restrict__ qh, u16* __restrict__ kh, u16* __restrict__ vth) {
    int mt = blockIdx.x, ot = blockIdx.y, b = blockIdx.z;
    int mm0 = mt*64, oo0 = ot*64;
    __shared__ u16 S[64][264];
    __shared__ u16 W[64][264];
    __shared__ float dn[64];
    int tid = threadIdx.x;
    if (tid < 64) {
        int m = mm0 + tid;
        float a0 = (m+1 < MM) ? A[((size_t)(b*MM + m+1))*3 + 0] : 0.f;
        float a1 =               A[((size_t)(b*MM + m  ))*3 + 1];
        float a2 = (m-1 >= 0)  ? A[((size_t)(b*MM + m-1))*3 + 2] : 0.f;
        dn[tid] = ((a0 + a1) + a2) + 1e-12f;
    }
    __syncthreads();
    const float* Pb = P + (size_t)b*MM*3*CC;
    for (int idx = tid; idx < 64*64; idx += 256) {
        int r = idx >> 6, c4 = (idx & 63) << 2;
        int m = mm0 + r;
        float4 p0 = make_float4(0.f,0.f,0.f,0.f), p2 = make_float4(0.f,0.f,0.f,0.f);
        if (m+1 < MM) p0 = *(const float4*)&Pb[((size_t)(m+1)*3 + 0)*CC + c4];
        float4 p1 = *(const float4*)&Pb[((size_t)m*3 + 1)*CC + c4];
        if (m-1 >= 0) p2 = *(const float4*)&Pb[((size_t)(m-1)*3 + 2)*CC + c4];
        float d = dn[r];
        float sx = ((p0.x+p1.x)+p2.x)/d, sy = ((p0.y+p1.y)+p2.y)/d;
        float sz = ((p0.z+p1.z)+p2.z)/d, sw = ((p0.w+p1.w)+p2.w)/d;
        *(u16x4*)&S[r][c4] = (u16x4){f2bfu(sx), f2bfu(sy), f2bfu(sz), f2bfu(sw)};
        float4 wv = *(const float4*)&wqkv[(size_t)(oo0 + r)*CC + c4];
        *(u16x4*)&W[r][c4] = (u16x4){f2bfu(wv.x), f2bfu(wv.y), f2bfu(wv.z), f2bfu(wv.w)};
    }
    __syncthreads();
    int w = tid >> 6, l = tid & 63;
    f32x4 acc[4] = {{0.f,0.f,0.f,0.f},{0.f,0.f,0.f,0.f},{0.f,0.f,0.f,0.f},{0.f,0.f,0.f,0.f}};
    #pragma unroll
    for (int kc = 0; kc < 8; ++kc) {
        bf16x8 bf = *(const bf16x8*)&W[w*16 + (l&15)][kc*32 + ((l>>4)<<3)];
        #pragma unroll
        for (int nt = 0; nt < 4; ++nt) {
            bf16x8 af = *(const bf16x8*)&S[nt*16 + (l&15)][kc*32 + ((l>>4)<<3)];
            acc[nt] = __builtin_amdgcn_mfma_f32_16x16x32_bf16(af, bf, acc[nt], 0, 0, 0);
        }
    }
    int o = oo0 + w*16 + (l&15);
    int h = o / 96, rr = o % 96;
    int bh = b*HH + h;
    int m0 = mm0 + ((l>>4)<<2);
    #pragma unroll
    for (int nt = 0; nt < 4; ++nt) {
        #pragma unroll
        for (int r = 0; r < 4; ++r) {
            int m = m0 + nt*16 + r;
            float v = acc[nt][r];
            if (rr < 32)      qh[((size_t)bh*MM + m)*HD + rr]       = f2bfu(v * QSCALE);
            else if (rr < 64) kh[((size_t)bh*MM + m)*HD + (rr-32)]  = f2bfu(v);
            else              vth[((size_t)bh*HD + (rr-64))*MM + m] = f2bfu(v);
        }
    }
}

// K4b (MFMA, nn-partitioned): ses[p][bh][mm] = sum over nn-partition of exp(k_mm . q_nn)
__global__ void k4b_mfma(const u16* __restrict__ qh, const u16* __restrict__ kh,
                         float* __restrict__ ses) {
    int bx = blockIdx.x;
    int p = blockIdx.y;
    int bh = bx >> 5;                 // MM/64 = 32 tiles
    int mt = bx & 31;
    int mm0 = mt * 64;
    int tid = threadIdx.x, w = tid >> 6, l = tid & 63;
    bf16x8 af = *(const bf16x8*)&kh[((size_t)bh*MM + mm0 + w*16 + (l&15))*HD + ((l>>4)<<3)];
    __shared__ u16 Qlds[64][40];
    float rs0=0.f, rs1=0.f, rs2=0.f, rs3=0.f;
    int nnbeg = p * (MM/PP1), nnend = nnbeg + (MM/PP1);
    for (int nn0 = nnbeg; nn0 < nnend; nn0 += 64) {
        __syncthreads();
        {
            int r = tid >> 2, ch = tid & 3;
            *(bf16x8*)&Qlds[r][ch*8] =
                *(const bf16x8*)&qh[((size_t)bh*MM + nn0 + r)*HD + ch*8];
        }
        __syncthreads();
        #pragma unroll
        for (int nt = 0; nt < 4; ++nt) {
            bf16x8 bf = *(const bf16x8*)&Qlds[nt*16 + (l&15)][(l>>4)<<3];
            f32x4 acc = {0.f,0.f,0.f,0.f};
            acc = __builtin_amdgcn_mfma_f32_16x16x32_bf16(af, bf, acc, 0, 0, 0);
            rs0 += __expf(acc[0]); rs1 += __expf(acc[1]);
            rs2 += __expf(acc[2]); rs3 += __expf(acc[3]);
        }
    }
    float rs[4] = {rs0, rs1, rs2, rs3};
    #pragma unroll
    for (int r = 0; r < 4; ++r) {
        float v = rs[r];
        v += __shfl_xor(v, 1, 64);
        v += __shfl_xor(v, 2, 64);
        v += __shfl_xor(v, 4, 64);
        v += __shfl_xor(v, 8, 64);
        if ((l & 15) == 0)
            ses[((size_t)p*BB*HH + bh)*MM + mm0 + w*16 + ((l>>4)<<2) + r] = v;
    }
}

// K4c (MFMA, mm-partitioned, fused denominator merge):
//   part[p][b][nn][h*32+d] = sum over mm-partition of exp(k_mm.q_nn)*(1/sum_p ses)*v[mm][d]
__global__ void k4c_mfma(const u16* __restrict__ qh, const u16* __restrict__ kh,
                         const u16* __restrict__ vth, const float* __restrict__ ses,
                         float* __restrict__ part) {
    int bx = blockIdx.x;
    int p = blockIdx.y;
    int bh = bx >> 5;
    int ntile = bx & 31;
    int nn0 = ntile * 64;
    int b = bh >> 3, h = bh & 7;
    int tid = threadIdx.x, w = tid >> 6, l = tid & 63;
    bf16x8 qf[4];
    #pragma unroll
    for (int nt = 0; nt < 4; ++nt)
        qf[nt] = *(const bf16x8*)&qh[((size_t)bh*MM + nn0 + nt*16 + (l&15))*HD + ((l>>4)<<3)];
    __shared__ u16 Klds[64][40];
    __shared__ u16 Vtlds[32][72];
    __shared__ u16 Wlds[64][72];
    __shared__ float Rlds[64];
    f32x4 o0 = {0.f,0.f,0.f,0.f}, o1 = {0.f,0.f,0.f,0.f};
    int mmbeg = p * (MM/PPB), mmend = mmbeg + (MM/PPB);
    const size_t SESP = (size_t)BB*HH*MM;
    for (int mm0 = mmbeg; mm0 < mmend; mm0 += 64) {
        __syncthreads();
        {
            int r = tid >> 2, ch = tid & 3;
            *(bf16x8*)&Klds[r][ch*8] =
                *(const bf16x8*)&kh[((size_t)bh*MM + mm0 + r)*HD + ch*8];
            int d = tid >> 3, ch2 = tid & 7;
            *(bf16x8*)&Vtlds[d][ch2*8] =
                *(const bf16x8*)&vth[((size_t)bh*HD + d)*MM + mm0 + ch2*8];
            if (tid < 64) {
                size_t e = (size_t)bh*MM + mm0 + tid;
                float s = ses[e] + ses[SESP + e] + ses[2*SESP + e] + ses[3*SESP + e];
                Rlds[tid] = 1.0f / s;
            }
        }
        __syncthreads();
        {
            bf16x8 af = *(const bf16x8*)&Klds[w*16 + (l&15)][(l>>4)<<3];
            float ri[4];
            #pragma unroll
            for (int r = 0; r < 4; ++r) ri[r] = Rlds[w*16 + ((l>>4)<<2) + r];
            #pragma unroll
            for (int nt = 0; nt < 4; ++nt) {
                f32x4 s = {0.f,0.f,0.f,0.f};
                s = __builtin_amdgcn_mfma_f32_16x16x32_bf16(af, qf[nt], s, 0, 0, 0);
                unsigned p0 = (unsigned)f2bfu(__expf(s[0]) * ri[0])
                            | ((unsigned)f2bfu(__expf(s[1]) * ri[1]) << 16);
                unsigned p1 = (unsigned)f2bfu(__expf(s[2]) * ri[2])
                            | ((unsigned)f2bfu(__expf(s[3]) * ri[3]) << 16);
                uint2 pk; pk.x = p0; pk.y = p1;
                *(uint2*)&Wlds[nt*16 + (l&15)][w*16 + ((l>>4)<<2)] = pk;
            }
        }
        __syncthreads();
        #pragma unroll
        for (int ks = 0; ks < 2; ++ks) {
            bf16x8 a2 = *(const bf16x8*)&Wlds[w*16 + (l&15)][ks*32 + ((l>>4)<<3)];
            bf16x8 b20 = *(const bf16x8*)&Vtlds[(l&15)][ks*32 + ((l>>4)<<3)];
            bf16x8 b21 = *(const bf16x8*)&Vtlds[16 + (l&15)][ks*32 + ((l>>4)<<3)];
            o0 = __builtin_amdgcn_mfma_f32_16x16x32_bf16(a2, b20, o0, 0, 0, 0);
            o1 = __builtin_amdgcn_mfma_f32_16x16x32_bf16(a2, b21, o1, 0, 0, 0);
        }
    }
    int nnb = nn0 + w*16 + ((l>>4)<<2);
    int dcol = h*32 + (l&15);
    float* op = part + ((size_t)p*BB + b)*((size_t)MM*CC);
    #pragma unroll
    for (int r = 0; r < 4; ++r) {
        op[((size_t)nnb + r)*CC + dcol]      = o0[r];
        op[((size_t)nnb + r)*CC + dcol + 16] = o1[r];
    }
}

// K5 (MFMA, fused partial reduce): sf2r[b,o,m] = Wproj @ (sum_p part[p]) + bproj
__global__ void k5_mfma(const float* __restrict__ part, const float* __restrict__ wproj,
                        const float* __restrict__ bproj, float* __restrict__ sf2r) {
    int mt = blockIdx.x, ot = blockIdx.y, b = blockIdx.z;
    int mm0 = mt*64, oo0 = ot*64;
    __shared__ u16 S[64][264];
    __shared__ u16 W[64][264];
    int tid = threadIdx.x;
    const size_t PARTP = (size_t)BB*MM*CC;
    const float* pb = part + (size_t)b*MM*CC;
    for (int idx = tid; idx < 64*64; idx += 256) {
        int r = idx >> 6, c4 = (idx & 63) << 2;
        size_t e = (size_t)(mm0 + r)*CC + c4;
        float4 s0 = *(const float4*)&pb[e];
        float4 s1 = *(const float4*)&pb[PARTP + e];
        float4 s2 = *(const float4*)&pb[2*PARTP + e];
        float4 s3 = *(const float4*)&pb[3*PARTP + e];
        float sx = s0.x+s1.x+s2.x+s3.x, sy = s0.y+s1.y+s2.y+s3.y;
        float sz = s0.z+s1.z+s2.z+s3.z, sw = s0.w+s1.w+s2.w+s3.w;
        *(u16x4*)&S[r][c4] = (u16x4){f2bfu(sx), f2bfu(sy), f2bfu(sz), f2bfu(sw)};
        float4 wv = *(const float4*)&wproj[(size_t)(oo0 + r)*CC + c4];
        *(u16x4*)&W[r][c4] = (u16x4){f2bfu(wv.x), f2bfu(wv.y), f2bfu(wv.z), f2bfu(wv.w)};
    }
    __syncthreads();
    int w = tid >> 6, l = tid & 63;
    f32x4 acc[4] = {{0.f,0.f,0.f,0.f},{0.f,0.f,0.f,0.f},{0.f,0.f,0.f,0.f},{0.f,0.f,0.f,0.f}};
    #pragma unroll
    for (int kc = 0; kc < 8; ++kc) {
        bf16x8 bf = *(const bf16x8*)&W[w*16 + (l&15)][kc*32 + ((l>>4)<<3)];
        #pragma unroll
        for (int nt = 0; nt < 4; ++nt) {
            bf16x8 af = *(const bf16x8*)&S[nt*16 + (l&15)][kc*32 + ((l>>4)<<3)];
            acc[nt] = __builtin_amdgcn_mfma_f32_16x16x32_bf16(af, bf, acc[nt], 0, 0, 0);
        }
    }
    int o = oo0 + w*16 + (l&15);
    float bp = bproj[o];
    int m0 = mm0 + ((l>>4)<<2);
    #pragma unroll
    for (int nt = 0; nt < 4; ++nt) {
        #pragma unroll
        for (int r = 0; r < 4; ++r) {
            sf2r[((size_t)b*CC + o)*MM + m0 + nt*16 + r] = acc[nt][r] + bp;
        }
    }
}

// K6: out[b,c,j*16+i] = sum_k sf2r[b,c,j+k-1]*aff[b,j,i,k]  (fp32 output)
// grid = (MM/16, 4 c-quarters, BB); one barrier.
__global__ void k6_final(const float* __restrict__ sf2r, const float* __restrict__ aff,
                         float* __restrict__ out) {
    int jt = blockIdx.x, cq = blockIdx.y, b = blockIdx.z;
    int jb = jt*16, cq0 = cq*64;
    int tid = threadIdx.x;               // 256 tokens
    int jl = tid >> 4, il = tid & 15;
    int j = jb + jl;
    size_t abase = (((size_t)b*MM + j)*SN + il)*3;
    float a0 = aff[abase], a1 = aff[abase+1], a2 = aff[abase+2];
    __shared__ float stile[64][18];
    for (int idx = tid; idx < 64*18; idx += 256) {
        int cl = idx / 18, jo = idx % 18;
        int jj = jb - 1 + jo;
        stile[cl][jo] = (jj >= 0 && jj < MM) ? sf2r[((size_t)b*CC + cq0 + cl)*MM + jj] : 0.f;
    }
    __syncthreads();
    int t = jb*SN + tid;
    float* ob = out + (size_t)b*CC*NN + (size_t)cq0*NN + t;
    #pragma unroll 4
    for (int cl = 0; cl < 64; ++cl) {
        float v = stile[cl][jl]*a0 + stile[cl][jl+1]*a1 + stile[cl][jl+2]*a2;
        ob[(size_t)cl*NN] = v;
    }
}

extern "C" void kernel_launch(void* const* d_in, const int* in_sizes, int n_in,
                              void* d_out, int out_size, void* d_ws, size_t ws_size,
                              hipStream_t stream) {
    const float *x = nullptr, *wqkv = nullptr, *wproj = nullptr, *bproj = nullptr;
    for (int i = 0; i < n_in; ++i) {
        int sz = in_sizes[i];
        if (sz == BB*NN*CC)        x     = (const float*)d_in[i];
        else if (sz == 3*CC*CC)    wqkv  = (const float*)d_in[i];
        else if (sz == CC*CC)      wproj = (const float*)d_in[i];
        else if (sz == CC)         bproj = (const float*)d_in[i];
    }
    float* out = (float*)d_out;    // reference output dtype is float32
    char* ws = (char*)d_ws;
    const size_t MB = 1024*1024;
    // Workspace (28 MiB total; P aliases part — disjoint lifetimes)
    float* aff     = (float*)(ws);            // 0.75 MiB (k2p -> k6)
    float* sfbuf   = (float*)(ws + 1*MB);     // 4 MiB: sf (k1->k2p), then sf2r (k5->k6)
    u16*   qh      = (u16*)  (ws + 5*MB);     // 2 MiB bf16 [bh][m][32]
    u16*   kh      = (u16*)  (ws + 7*MB);     // 2 MiB bf16 [bh][m][32]
    u16*   vth     = (u16*)  (ws + 9*MB);     // 2 MiB bf16 [bh][32][m]
    float* ses     = (float*)(ws + 11*MB);    // 0.5 MiB (PP1 partials, k4b->k4c)
    float* A       = (float*)(ws + 11*MB + 512*1024);  // 48 KiB (k2p->k4a)
    float* P       = (float*)(ws + 12*MB);    // 12.6 MiB (k2p->k4a)
    float* part    = (float*)(ws + 12*MB);    // 16 MiB (k4c->k5), aliases P
    float* sf      = sfbuf;
    float* sf2r    = sfbuf;

    k1_sf   <<<BB*MM, 256, 0, stream>>>(x, sf);
    k2p_aff <<<BB*MM, 256, 0, stream>>>(x, sf, aff, P, A);
    k4a_mfma<<<dim3(MM/64, 12, BB), 256, 0, stream>>>(P, A, wqkv, qh, kh, vth);
    k4b_mfma<<<dim3(BB*HH*(MM/64), PP1), 256, 0, stream>>>(qh, kh, ses);
    k4c_mfma<<<dim3(BB*HH*(MM/64), PPB), 256, 0, stream>>>(qh, kh, vth, ses, part);
    k5_mfma <<<dim3(MM/64, 4, BB), 256, 0, stream>>>(part, wproj, bproj, sf2r);
    k6_final<<<dim3(MM/16, 4, BB), 256, 0, stream>>>(sf2r, aff, out);
}

// Round 13
// 124.298 us; speedup vs baseline: 1.1454x; 1.0235x over previous
//
#include <hip/hip_runtime.h>
#include <hip/hip_bf16.h>

#define BB 2
#define NN 32768
#define CC 256
#define SN 16
#define MM 2048          // NN/SN
#define HH 8
#define HD 32
#define PP1 4            // nn-partitions for denominator pass
#define PPB 4            // mm-partitions for output pass
#define QSCALE 0.17677669529663687f   // 1/sqrt(32)
#define AFFSCALE 0.0625f              // C^-0.5

typedef unsigned short u16;
typedef __attribute__((ext_vector_type(8))) short bf16x8;
typedef __attribute__((ext_vector_type(4))) float f32x4;
typedef __attribute__((ext_vector_type(4))) unsigned short u16x4;

// RNE float->bf16 bits
__device__ __forceinline__ u16 f2bfu(float x) {
    unsigned u = __float_as_uint(x);
    u = (u + 0x7fff + ((u >> 16) & 1)) >> 16;
    return (u16)u;
}

// load 8 consecutive fp32 from global, convert RNE -> bf16x8 fragment
__device__ __forceinline__ bf16x8 ld_w8(const float* __restrict__ p) {
    float4 a = *(const float4*)p;
    float4 b = *(const float4*)(p + 4);
    bf16x8 r;
    r[0] = (short)f2bfu(a.x); r[1] = (short)f2bfu(a.y);
    r[2] = (short)f2bfu(a.z); r[3] = (short)f2bfu(a.w);
    r[4] = (short)f2bfu(b.x); r[5] = (short)f2bfu(b.y);
    r[6] = (short)f2bfu(b.z); r[7] = (short)f2bfu(b.w);
    return r;
}

// K1: sf[b,j,c] = mean over 16 tokens
__global__ void k1_sf(const float* __restrict__ x, float* __restrict__ sf) {
    int blk = blockIdx.x;           // b*MM + j
    int b = blk / MM, j = blk % MM;
    int c = threadIdx.x;
    const float* xp = x + ((size_t)(b*NN + j*SN))*CC + c;
    float s = 0.f;
    #pragma unroll
    for (int i = 0; i < SN; ++i) s += xp[i*CC];
    sf[(size_t)blk*CC + c] = s * (1.0f/16.0f);
}

// K2P: aff[b,j,i,k] = softmax_k( pix . sf[j+k-1] * scale )
//  + fold partials local to this block:
//    P[b,j,k,c] = sum_i x[j,i,c]*aff[j,i,k]
//    A[b,j,k]   = sum_i aff[j,i,k]
__global__ void k2p_aff(const float* __restrict__ x, const float* __restrict__ sf,
                        float* __restrict__ aff, float* __restrict__ P,
                        float* __restrict__ A) {
    int blk = blockIdx.x; int b = blk / MM, j = blk % MM;
    __shared__ float sfl[3][CC];
    __shared__ float xl[SN][CC];
    __shared__ float affl[SN][3];
    int tid = threadIdx.x;
    #pragma unroll
    for (int k = 0; k < 3; ++k) {
        int w = j + k - 1;
        sfl[k][tid] = (w >= 0 && w < MM) ? sf[((size_t)b*MM + w)*CC + tid] : 0.f;
    }
    for (int idx = tid; idx < SN*64; idx += 256) {
        int i = idx >> 6, c4 = (idx & 63) << 2;
        *(float4*)&xl[i][c4] = *(const float4*)&x[((size_t)(b*NN + j*SN + i))*CC + c4];
    }
    __syncthreads();
    int wave = tid >> 6, lane = tid & 63;
    for (int qi = 0; qi < 4; ++qi) {
        int i = wave*4 + qi;
        float d0=0.f, d1=0.f, d2=0.f;
        #pragma unroll
        for (int cq = 0; cq < 4; ++cq) {
            int c = lane + cq*64;
            float xv = xl[i][c];
            d0 += xv * sfl[0][c];
            d1 += xv * sfl[1][c];
            d2 += xv * sfl[2][c];
        }
        #pragma unroll
        for (int off = 32; off >= 1; off >>= 1) {
            d0 += __shfl_xor(d0, off, 64);
            d1 += __shfl_xor(d1, off, 64);
            d2 += __shfl_xor(d2, off, 64);
        }
        if (lane == 0) {
            float l0 = d0*AFFSCALE, l1 = d1*AFFSCALE, l2 = d2*AFFSCALE;
            float mx = fmaxf(l0, fmaxf(l1, l2));
            float e0 = __expf(l0-mx), e1 = __expf(l1-mx), e2 = __expf(l2-mx);
            float inv = 1.0f/(e0+e1+e2);
            float a0 = e0*inv, a1 = e1*inv, a2 = e2*inv;
            size_t base = ((size_t)blk*SN + i)*3;
            aff[base+0] = a0; aff[base+1] = a1; aff[base+2] = a2;
            affl[i][0] = a0; affl[i][1] = a1; affl[i][2] = a2;
        }
    }
    __syncthreads();
    {
        int c = tid;
        #pragma unroll
        for (int k = 0; k < 3; ++k) {
            float p = 0.f;
            #pragma unroll
            for (int i = 0; i < SN; ++i) p += xl[i][c] * affl[i][k];
            P[((size_t)blk*3 + k)*CC + c] = p;
        }
        if (tid < 3) {
            float a = 0.f;
            #pragma unroll
            for (int i = 0; i < SN; ++i) a += affl[i][tid];
            A[(size_t)blk*3 + tid] = a;
        }
    }
}

// K4a (MFMA, fused fold/normalize, W direct from L2 — no W LDS tile):
//   sf2[m,c] = (P[m+1][0][c] + P[m][1][c] + P[m-1][2][c]) / (A-fold + 1e-12)
__global__ void k4a_mfma(const float* __restrict__ P, const float* __restrict__ A,
                         const float* __restrict__ wqkv,
                         u16* __restrict__ qh, u16* __restrict__ kh, u16* __restrict__ vth) {
    int mt = blockIdx.x, ot = blockIdx.y, b = blockIdx.z;
    int mm0 = mt*64, oo0 = ot*64;
    __shared__ u16 S[64][264];
    __shared__ float dn[64];
    int tid = threadIdx.x;
    if (tid < 64) {
        int m = mm0 + tid;
        float a0 = (m+1 < MM) ? A[((size_t)(b*MM + m+1))*3 + 0] : 0.f;
        float a1 =               A[((size_t)(b*MM + m  ))*3 + 1];
        float a2 = (m-1 >= 0)  ? A[((size_t)(b*MM + m-1))*3 + 2] : 0.f;
        dn[tid] = ((a0 + a1) + a2) + 1e-12f;
    }
    __syncthreads();
    const float* Pb = P + (size_t)b*MM*3*CC;
    for (int idx = tid; idx < 64*64; idx += 256) {
        int r = idx >> 6, c4 = (idx & 63) << 2;
        int m = mm0 + r;
        float4 p0 = make_float4(0.f,0.f,0.f,0.f), p2 = make_float4(0.f,0.f,0.f,0.f);
        if (m+1 < MM) p0 = *(const float4*)&Pb[((size_t)(m+1)*3 + 0)*CC + c4];
        float4 p1 = *(const float4*)&Pb[((size_t)m*3 + 1)*CC + c4];
        if (m-1 >= 0) p2 = *(const float4*)&Pb[((size_t)(m-1)*3 + 2)*CC + c4];
        float d = dn[r];
        float sx = ((p0.x+p1.x)+p2.x)/d, sy = ((p0.y+p1.y)+p2.y)/d;
        float sz = ((p0.z+p1.z)+p2.z)/d, sw = ((p0.w+p1.w)+p2.w)/d;
        *(u16x4*)&S[r][c4] = (u16x4){f2bfu(sx), f2bfu(sy), f2bfu(sz), f2bfu(sw)};
    }
    __syncthreads();
    int w = tid >> 6, l = tid & 63;
    // B-frag row (o) and k-chunk offset for direct global loads
    const float* wrow = wqkv + (size_t)(oo0 + w*16 + (l&15))*CC + ((l>>4)<<3);
    f32x4 acc[4] = {{0.f,0.f,0.f,0.f},{0.f,0.f,0.f,0.f},{0.f,0.f,0.f,0.f},{0.f,0.f,0.f,0.f}};
    #pragma unroll
    for (int kc = 0; kc < 8; ++kc) {
        bf16x8 bf = ld_w8(wrow + kc*32);
        #pragma unroll
        for (int nt = 0; nt < 4; ++nt) {
            bf16x8 af = *(const bf16x8*)&S[nt*16 + (l&15)][kc*32 + ((l>>4)<<3)];
            acc[nt] = __builtin_amdgcn_mfma_f32_16x16x32_bf16(af, bf, acc[nt], 0, 0, 0);
        }
    }
    int o = oo0 + w*16 + (l&15);
    int h = o / 96, rr = o % 96;
    int bh = b*HH + h;
    int m0 = mm0 + ((l>>4)<<2);
    #pragma unroll
    for (int nt = 0; nt < 4; ++nt) {
        #pragma unroll
        for (int r = 0; r < 4; ++r) {
            int m = m0 + nt*16 + r;
            float v = acc[nt][r];
            if (rr < 32)      qh[((size_t)bh*MM + m)*HD + rr]       = f2bfu(v * QSCALE);
            else if (rr < 64) kh[((size_t)bh*MM + m)*HD + (rr-32)]  = f2bfu(v);
            else              vth[((size_t)bh*HD + (rr-64))*MM + m] = f2bfu(v);
        }
    }
}

// K4b (MFMA, nn-partitioned): ses[p][bh][mm] = sum over nn-partition of exp(k_mm . q_nn)
__global__ void k4b_mfma(const u16* __restrict__ qh, const u16* __restrict__ kh,
                         float* __restrict__ ses) {
    int bx = blockIdx.x;
    int p = blockIdx.y;
    int bh = bx >> 5;                 // MM/64 = 32 tiles
    int mt = bx & 31;
    int mm0 = mt * 64;
    int tid = threadIdx.x, w = tid >> 6, l = tid & 63;
    bf16x8 af = *(const bf16x8*)&kh[((size_t)bh*MM + mm0 + w*16 + (l&15))*HD + ((l>>4)<<3)];
    __shared__ u16 Qlds[64][40];
    float rs0=0.f, rs1=0.f, rs2=0.f, rs3=0.f;
    int nnbeg = p * (MM/PP1), nnend = nnbeg + (MM/PP1);
    for (int nn0 = nnbeg; nn0 < nnend; nn0 += 64) {
        __syncthreads();
        {
            int r = tid >> 2, ch = tid & 3;
            *(bf16x8*)&Qlds[r][ch*8] =
                *(const bf16x8*)&qh[((size_t)bh*MM + nn0 + r)*HD + ch*8];
        }
        __syncthreads();
        #pragma unroll
        for (int nt = 0; nt < 4; ++nt) {
            bf16x8 bf = *(const bf16x8*)&Qlds[nt*16 + (l&15)][(l>>4)<<3];
            f32x4 acc = {0.f,0.f,0.f,0.f};
            acc = __builtin_amdgcn_mfma_f32_16x16x32_bf16(af, bf, acc, 0, 0, 0);
            rs0 += __expf(acc[0]); rs1 += __expf(acc[1]);
            rs2 += __expf(acc[2]); rs3 += __expf(acc[3]);
        }
    }
    float rs[4] = {rs0, rs1, rs2, rs3};
    #pragma unroll
    for (int r = 0; r < 4; ++r) {
        float v = rs[r];
        v += __shfl_xor(v, 1, 64);
        v += __shfl_xor(v, 2, 64);
        v += __shfl_xor(v, 4, 64);
        v += __shfl_xor(v, 8, 64);
        if ((l & 15) == 0)
            ses[((size_t)p*BB*HH + bh)*MM + mm0 + w*16 + ((l>>4)<<2) + r] = v;
    }
}

// K4c (MFMA, mm-partitioned, fused denominator merge):
//   part[p][b][nn][h*32+d] = sum over mm-partition of exp(k_mm.q_nn)*(1/sum_p ses)*v[mm][d]
__global__ void k4c_mfma(const u16* __restrict__ qh, const u16* __restrict__ kh,
                         const u16* __restrict__ vth, const float* __restrict__ ses,
                         float* __restrict__ part) {
    int bx = blockIdx.x;
    int p = blockIdx.y;
    int bh = bx >> 5;
    int ntile = bx & 31;
    int nn0 = ntile * 64;
    int b = bh >> 3, h = bh & 7;
    int tid = threadIdx.x, w = tid >> 6, l = tid & 63;
    bf16x8 qf[4];
    #pragma unroll
    for (int nt = 0; nt < 4; ++nt)
        qf[nt] = *(const bf16x8*)&qh[((size_t)bh*MM + nn0 + nt*16 + (l&15))*HD + ((l>>4)<<3)];
    __shared__ u16 Klds[64][40];
    __shared__ u16 Vtlds[32][72];
    __shared__ u16 Wlds[64][72];
    __shared__ float Rlds[64];
    f32x4 o0 = {0.f,0.f,0.f,0.f}, o1 = {0.f,0.f,0.f,0.f};
    int mmbeg = p * (MM/PPB), mmend = mmbeg + (MM/PPB);
    const size_t SESP = (size_t)BB*HH*MM;
    for (int mm0 = mmbeg; mm0 < mmend; mm0 += 64) {
        __syncthreads();
        {
            int r = tid >> 2, ch = tid & 3;
            *(bf16x8*)&Klds[r][ch*8] =
                *(const bf16x8*)&kh[((size_t)bh*MM + mm0 + r)*HD + ch*8];
            int d = tid >> 3, ch2 = tid & 7;
            *(bf16x8*)&Vtlds[d][ch2*8] =
                *(const bf16x8*)&vth[((size_t)bh*HD + d)*MM + mm0 + ch2*8];
            if (tid < 64) {
                size_t e = (size_t)bh*MM + mm0 + tid;
                float s = ses[e] + ses[SESP + e] + ses[2*SESP + e] + ses[3*SESP + e];
                Rlds[tid] = 1.0f / s;
            }
        }
        __syncthreads();
        {
            bf16x8 af = *(const bf16x8*)&Klds[w*16 + (l&15)][(l>>4)<<3];
            float ri[4];
            #pragma unroll
            for (int r = 0; r < 4; ++r) ri[r] = Rlds[w*16 + ((l>>4)<<2) + r];
            #pragma unroll
            for (int nt = 0; nt < 4; ++nt) {
                f32x4 s = {0.f,0.f,0.f,0.f};
                s = __builtin_amdgcn_mfma_f32_16x16x32_bf16(af, qf[nt], s, 0, 0, 0);
                unsigned p0 = (unsigned)f2bfu(__expf(s[0]) * ri[0])
                            | ((unsigned)f2bfu(__expf(s[1]) * ri[1]) << 16);
                unsigned p1 = (unsigned)f2bfu(__expf(s[2]) * ri[2])
                            | ((unsigned)f2bfu(__expf(s[3]) * ri[3]) << 16);
                uint2 pk; pk.x = p0; pk.y = p1;
                *(uint2*)&Wlds[nt*16 + (l&15)][w*16 + ((l>>4)<<2)] = pk;
            }
        }
        __syncthreads();
        #pragma unroll
        for (int ks = 0; ks < 2; ++ks) {
            bf16x8 a2 = *(const bf16x8*)&Wlds[w*16 + (l&15)][ks*32 + ((l>>4)<<3)];
            bf16x8 b20 = *(const bf16x8*)&Vtlds[(l&15)][ks*32 + ((l>>4)<<3)];
            bf16x8 b21 = *(const bf16x8*)&Vtlds[16 + (l&15)][ks*32 + ((l>>4)<<3)];
            o0 = __builtin_amdgcn_mfma_f32_16x16x32_bf16(a2, b20, o0, 0, 0, 0);
            o1 = __builtin_amdgcn_mfma_f32_16x16x32_bf16(a2, b21, o1, 0, 0, 0);
        }
    }
    int nnb = nn0 + w*16 + ((l>>4)<<2);
    int dcol = h*32 + (l&15);
    float* op = part + ((size_t)p*BB + b)*((size_t)MM*CC);
    #pragma unroll
    for (int r = 0; r < 4; ++r) {
        op[((size_t)nnb + r)*CC + dcol]      = o0[r];
        op[((size_t)nnb + r)*CC + dcol + 16] = o1[r];
    }
}

// K5 (MFMA, fused partial reduce, W direct from L2 — no W LDS tile):
//   sf2r[b,o,m] = Wproj @ (sum_p part[p]) + bproj
__global__ void k5_mfma(const float* __restrict__ part, const float* __restrict__ wproj,
                        const float* __restrict__ bproj, float* __restrict__ sf2r) {
    int mt = blockIdx.x, ot = blockIdx.y, b = blockIdx.z;
    int mm0 = mt*64, oo0 = ot*64;
    __shared__ u16 S[64][264];
    int tid = threadIdx.x;
    const size_t PARTP = (size_t)BB*MM*CC;
    const float* pb = part + (size_t)b*MM*CC;
    for (int idx = tid; idx < 64*64; idx += 256) {
        int r = idx >> 6, c4 = (idx & 63) << 2;
        size_t e = (size_t)(mm0 + r)*CC + c4;
        float4 s0 = *(const float4*)&pb[e];
        float4 s1 = *(const float4*)&pb[PARTP + e];
        float4 s2 = *(const float4*)&pb[2*PARTP + e];
        float4 s3 = *(const float4*)&pb[3*PARTP + e];
        float sx = s0.x+s1.x+s2.x+s3.x, sy = s0.y+s1.y+s2.y+s3.y;
        float sz = s0.z+s1.z+s2.z+s3.z, sw = s0.w+s1.w+s2.w+s3.w;
        *(u16x4*)&S[r][c4] = (u16x4){f2bfu(sx), f2bfu(sy), f2bfu(sz), f2bfu(sw)};
    }
    __syncthreads();
    int w = tid >> 6, l = tid & 63;
    const float* wrow = wproj + (size_t)(oo0 + w*16 + (l&15))*CC + ((l>>4)<<3);
    f32x4 acc[4] = {{0.f,0.f,0.f,0.f},{0.f,0.f,0.f,0.f},{0.f,0.f,0.f,0.f},{0.f,0.f,0.f,0.f}};
    #pragma unroll
    for (int kc = 0; kc < 8; ++kc) {
        bf16x8 bf = ld_w8(wrow + kc*32);
        #pragma unroll
        for (int nt = 0; nt < 4; ++nt) {
            bf16x8 af = *(const bf16x8*)&S[nt*16 + (l&15)][kc*32 + ((l>>4)<<3)];
            acc[nt] = __builtin_amdgcn_mfma_f32_16x16x32_bf16(af, bf, acc[nt], 0, 0, 0);
        }
    }
    int o = oo0 + w*16 + (l&15);
    float bp = bproj[o];
    int m0 = mm0 + ((l>>4)<<2);
    #pragma unroll
    for (int nt = 0; nt < 4; ++nt) {
        #pragma unroll
        for (int r = 0; r < 4; ++r) {
            sf2r[((size_t)b*CC + o)*MM + m0 + nt*16 + r] = acc[nt][r] + bp;
        }
    }
}

// K6: out[b,c,j*16+i] = sum_k sf2r[b,c,j+k-1]*aff[b,j,i,k]  (fp32 output)
// grid = (MM/16, 4 c-quarters, BB); one barrier.
__global__ void k6_final(const float* __restrict__ sf2r, const float* __restrict__ aff,
                         float* __restrict__ out) {
    int jt = blockIdx.x, cq = blockIdx.y, b = blockIdx.z;
    int jb = jt*16, cq0 = cq*64;
    int tid = threadIdx.x;               // 256 tokens
    int jl = tid >> 4, il = tid & 15;
    int j = jb + jl;
    size_t abase = (((size_t)b*MM + j)*SN + il)*3;
    float a0 = aff[abase], a1 = aff[abase+1], a2 = aff[abase+2];
    __shared__ float stile[64][18];
    for (int idx = tid; idx < 64*18; idx += 256) {
        int cl = idx / 18, jo = idx % 18;
        int jj = jb - 1 + jo;
        stile[cl][jo] = (jj >= 0 && jj < MM) ? sf2r[((size_t)b*CC + cq0 + cl)*MM + jj] : 0.f;
    }
    __syncthreads();
    int t = jb*SN + tid;
    float* ob = out + (size_t)b*CC*NN + (size_t)cq0*NN + t;
    #pragma unroll 4
    for (int cl = 0; cl < 64; ++cl) {
        float v = stile[cl][jl]*a0 + stile[cl][jl+1]*a1 + stile[cl][jl+2]*a2;
        ob[(size_t)cl*NN] = v;
    }
}

extern "C" void kernel_launch(void* const* d_in, const int* in_sizes, int n_in,
                              void* d_out, int out_size, void* d_ws, size_t ws_size,
                              hipStream_t stream) {
    const float *x = nullptr, *wqkv = nullptr, *wproj = nullptr, *bproj = nullptr;
    for (int i = 0; i < n_in; ++i) {
        int sz = in_sizes[i];
        if (sz == BB*NN*CC)        x     = (const float*)d_in[i];
        else if (sz == 3*CC*CC)    wqkv  = (const float*)d_in[i];
        else if (sz == CC*CC)      wproj = (const float*)d_in[i];
        else if (sz == CC)         bproj = (const float*)d_in[i];
    }
    float* out = (float*)d_out;    // reference output dtype is float32
    char* ws = (char*)d_ws;
    const size_t MB = 1024*1024;
    // Workspace (28 MiB total; P aliases part — disjoint lifetimes)
    float* aff     = (float*)(ws);            // 0.75 MiB (k2p -> k6)
    float* sfbuf   = (float*)(ws + 1*MB);     // 4 MiB: sf (k1->k2p), then sf2r (k5->k6)
    u16*   qh      = (u16*)  (ws + 5*MB);     // 2 MiB bf16 [bh][m][32]
    u16*   kh      = (u16*)  (ws + 7*MB);     // 2 MiB bf16 [bh][m][32]
    u16*   vth     = (u16*)  (ws + 9*MB);     // 2 MiB bf16 [bh][32][m]
    float* ses     = (float*)(ws + 11*MB);    // 0.5 MiB (PP1 partials, k4b->k4c)
    float* A       = (float*)(ws + 11*MB + 512*1024);  // 48 KiB (k2p->k4a)
    float* P       = (float*)(ws + 12*MB);    // 12.6 MiB (k2p->k4a)
    float* part    = (float*)(ws + 12*MB);    // 16 MiB (k4c->k5), aliases P
    float* sf      = sfbuf;
    float* sf2r    = sfbuf;

    k1_sf   <<<BB*MM, 256, 0, stream>>>(x, sf);
    k2p_aff <<<BB*MM, 256, 0, stream>>>(x, sf, aff, P, A);
    k4a_mfma<<<dim3(MM/64, 12, BB), 256, 0, stream>>>(P, A, wqkv, qh, kh, vth);
    k4b_mfma<<<dim3(BB*HH*(MM/64), PP1), 256, 0, stream>>>(qh, kh, ses);
    k4c_mfma<<<dim3(BB*HH*(MM/64), PPB), 256, 0, stream>>>(qh, kh, vth, ses, part);
    k5_mfma <<<dim3(MM/64, 4, BB), 256, 0, stream>>>(part, wproj, bproj, sf2r);
    k6_final<<<dim3(MM/16, 4, BB), 256, 0, stream>>>(sf2r, aff, out);
}